// Round 5
// baseline (1079.764 us; speedup 1.0000x reference)
//
#include <hip/hip_runtime.h>
#include <hip/hip_bf16.h>
#include <math.h>

#define NN 20000
#define EE 320000
#define QKV_COLS 1152   // [q 0..383 | k 384..767 | v 768..1151]
#define PTS_COLS 864    // [qp 0..287 | kp 288..575 | vp 576..863]
#define FCOLS 1440      // [p2n 384 | node 384 | loc 288 | nrm 96 | dirn 288]
#define KE_COLS 768     // 12 heads x 64 [k 32 | kp 24 | 0 | 1 | 0 x6]

__device__ __forceinline__ float b2f(unsigned short u) {
  return __uint_as_float(((unsigned)u) << 16);
}

template<typename PT> __device__ __forceinline__ float ldp(const PT* p);
template<> __device__ __forceinline__ float ldp<float>(const float* p) { return *p; }
template<> __device__ __forceinline__ float ldp<__hip_bfloat16>(const __hip_bfloat16* p) { return __bfloat162float(*p); }
template<typename PT> __device__ __forceinline__ void stp(PT* p, float v);
template<> __device__ __forceinline__ void stp<float>(float* p, float v) { *p = v; }
template<> __device__ __forceinline__ void stp<__hip_bfloat16>(__hip_bfloat16* p, float v) { *p = __float2bfloat16(v); }

// ---------------- projections: [Pqkv | Ppts](n) = x[n] @ [Wq|Wk|Wv | Wqp|Wkp|Wvp]
template<typename TA, typename TP>
__global__ __launch_bounds__(256) void proj_gemm(
    const float* __restrict__ x,
    const float* __restrict__ Wq, const float* __restrict__ Wk, const float* __restrict__ Wv,
    const float* __restrict__ Wqp, const float* __restrict__ Wkp, const float* __restrict__ Wvp,
    TA* __restrict__ Pqkv, TP* __restrict__ Ppts)
{
  __shared__ float Ast[32][36];
  __shared__ float Bs[32][132];
  const int t = threadIdx.x;
  const int n0 = blockIdx.x * 32;
  const int c0 = blockIdx.y * 128;
  const int tx = t & 31, ty = t >> 5;
  const int cl = t & 127, kset = t >> 7;
  const int c = c0 + cl;
  const float* wcol = nullptr; int wstr = 0;
  if      (c < 384)  { wcol = Wq  + c;        wstr = 384; }
  else if (c < 768)  { wcol = Wk  + (c-384);  wstr = 384; }
  else if (c < 1152) { wcol = Wv  + (c-768);  wstr = 384; }
  else if (c < 1440) { wcol = Wqp + (c-1152); wstr = 288; }
  else if (c < 1728) { wcol = Wkp + (c-1440); wstr = 288; }
  else if (c < 2016) { wcol = Wvp + (c-1728); wstr = 288; }
  float acc[4][4] = {};
  const int ar = t >> 3, akc = (t & 7) * 4;
  for (int k0 = 0; k0 < 128; k0 += 32) {
    float4 av4 = *(const float4*)&x[(size_t)(n0 + ar)*128 + k0 + akc];
    Ast[akc+0][ar] = av4.x; Ast[akc+1][ar] = av4.y;
    Ast[akc+2][ar] = av4.z; Ast[akc+3][ar] = av4.w;
    #pragma unroll
    for (int u = 0; u < 16; u++) {
      int kk = kset + 2*u;
      Bs[kk][cl] = wcol ? wcol[(size_t)(k0 + kk)*wstr] : 0.f;
    }
    __syncthreads();
    #pragma unroll
    for (int kk = 0; kk < 32; kk++) {
      float4 a4 = *(const float4*)&Ast[kk][ty*4];
      float4 b4 = *(const float4*)&Bs[kk][tx*4];
      float av[4] = {a4.x, a4.y, a4.z, a4.w};
      float bv[4] = {b4.x, b4.y, b4.z, b4.w};
      #pragma unroll
      for (int i2 = 0; i2 < 4; i2++)
        #pragma unroll
        for (int j2 = 0; j2 < 4; j2++)
          acc[i2][j2] += av[i2] * bv[j2];
    }
    __syncthreads();
  }
  const int gc = c0 + tx*4;
  #pragma unroll
  for (int i2 = 0; i2 < 4; i2++) {
    int r = n0 + ty*4 + i2;
    if (gc < 1152) {
      TA* dstp = Pqkv + (size_t)r*QKV_COLS + gc;
      #pragma unroll
      for (int j2 = 0; j2 < 4; j2++) stp(&dstp[j2], acc[i2][j2]);
    } else {
      TP* dstp = Ppts + (size_t)r*PTS_COLS + (gc - 1152);
      #pragma unroll
      for (int j2 = 0; j2 < 4; j2++) if (gc + j2 < 2016) stp(&dstp[j2], acc[i2][j2]);
    }
  }
}

// ---------------- point transform (in place on Ppts): p_global = R p_local + t
template<typename TP>
__global__ void transform_pts(const float* __restrict__ R, const float* __restrict__ tr,
                              TP* __restrict__ Ppts)
{
  int idx = blockIdx.x*256 + threadIdx.x;   // N * 288 point-triples
  if (idx >= NN*288) return;
  int n = idx / 288, rem = idx - n*288;
  TP* p = Ppts + (size_t)n*PTS_COLS + rem*3;
  float l0 = ldp(p), l1 = ldp(p+1), l2 = ldp(p+2);
  const float* Rn = R + (size_t)n*9;
  float t0 = tr[n*3], t1 = tr[n*3+1], t2 = tr[n*3+2];
  stp(p,   Rn[0]*l0 + Rn[1]*l1 + Rn[2]*l2 + t0);
  stp(p+1, Rn[3]*l0 + Rn[4]*l1 + Rn[5]*l2 + t1);
  stp(p+2, Rn[6]*l0 + Rn[7]*l1 + Rn[8]*l2 + t2);
}

// ---------------- CSR build
__global__ void count_edges(const int* __restrict__ ei, int* __restrict__ cnt)
{
  int e = blockIdx.x*256 + threadIdx.x;
  if (e < EE) atomicAdd(&cnt[ei[e]], 1);
}

__global__ __launch_bounds__(1024) void scan_csr(const int* __restrict__ cnt,
                                                 int* __restrict__ rowptr,
                                                 int* __restrict__ cursor)
{
  __shared__ int part[1024];
  int t = threadIdx.x;
  int base = t*20;
  int loc[20];
  int s = 0;
  #pragma unroll
  for (int i = 0; i < 20; i++) {
    int idx = base + i;
    int cc = (idx < NN) ? cnt[idx] : 0;
    loc[i] = s; s += cc;
  }
  part[t] = s;
  __syncthreads();
  for (int off = 1; off < 1024; off <<= 1) {
    int v = (t >= off) ? part[t-off] : 0;
    __syncthreads();
    part[t] += v;
    __syncthreads();
  }
  int pre = (t == 0) ? 0 : part[t-1];
  #pragma unroll
  for (int i = 0; i < 20; i++) {
    int idx = base + i;
    if (idx < NN) { rowptr[idx] = pre + loc[i]; cursor[idx] = pre + loc[i]; }
  }
  if (t == 1023) rowptr[NN] = part[1023];
}

__global__ void fill_csr(const int* __restrict__ ei, int* __restrict__ cursor,
                         int* __restrict__ eidx)
{
  int e = blockIdx.x*256 + threadIdx.x;
  if (e >= EE) return;
  int pos = atomicAdd(&cursor[ei[e]], 1);
  eidx[pos] = e;
}

// ---------------- build Ke panel + SKKP (dst-side constants)
// Ke[n][h*64 + i] = [ k(32) | kp_global(24) | 0 | 1 | 0 x6 ]   (bf16)
// SKKP[n*12+h]   = -sqrt(1/3) * cf_h * sum(kp_global^2)         (f32)
template<typename TA, typename TP>
__global__ __launch_bounds__(256) void build_ke(
    const TA* __restrict__ Pqkv, const TP* __restrict__ Ppts,
    const float* __restrict__ spc,
    __hip_bfloat16* __restrict__ KE, float* __restrict__ SKKP)
{
  __shared__ float skk[12], cfb[12];
  const int n = blockIdx.x, t = threadIdx.x;
  if (t < 12) { cfb[t] = log1pf(expf(spc[t])) * (1.f/12.f); skk[t] = 0.f; }
  __syncthreads();
  for (int s = t; s < 288; s += 256) {          // FIX: was `if (t < 288)` with 256 threads
    float v = ldp(&Ppts[(size_t)n*PTS_COLS + 288 + s]);
    atomicAdd(&skk[s/24], v*v);
  }
  __syncthreads();
  __hip_bfloat16* kr = KE + (size_t)n*KE_COLS;
  #pragma unroll
  for (int u = 0; u < 3; u++) {
    int s = t + 256*u;
    int h = s >> 6, i = s & 63;
    float val = 0.f;
    if (i < 32)       val = ldp(&Pqkv[(size_t)n*QKV_COLS + 384 + h*32 + i]);
    else if (i < 56)  val = ldp(&Ppts[(size_t)n*PTS_COLS + 288 + h*24 + (i-32)]);
    else if (i == 57) val = 1.0f;
    kr[s] = __float2bfloat16(val);
  }
  if (t < 12) SKKP[(size_t)n*12 + t] = -0.57735026919f * cfb[t] * skk[t];
}

__device__ __forceinline__ float dot8(const float* qr, uint4 v) {
  float s;
  s  = qr[0]*b2f((unsigned short)(v.x & 0xffffu));
  s += qr[1]*b2f((unsigned short)(v.x >> 16));
  s += qr[2]*b2f((unsigned short)(v.y & 0xffffu));
  s += qr[3]*b2f((unsigned short)(v.y >> 16));
  s += qr[4]*b2f((unsigned short)(v.z & 0xffffu));
  s += qr[5]*b2f((unsigned short)(v.z >> 16));
  s += qr[6]*b2f((unsigned short)(v.w & 0xffffu));
  s += qr[7]*b2f((unsigned short)(v.w >> 16));
  return s;
}

// ---------------- fused flash-style attention: logits + online softmax + aggregation
template<typename TA, typename TP>
__global__ __launch_bounds__(256) void attn_fused(
    const TA* __restrict__ Pqkv, const TP* __restrict__ Ppts,
    const __hip_bfloat16* __restrict__ KE, const float* __restrict__ SKKP,
    const float* __restrict__ z, const int* __restrict__ ei,
    const float* __restrict__ Wpair, const float* __restrict__ spc,
    const int* __restrict__ rowptr, const int* __restrict__ eidx,
    const float* __restrict__ R, const float* __restrict__ tr,
    __hip_bfloat16* __restrict__ featB)
{
  __shared__ float qe[768];
  __shared__ float wpT[12*33];
  __shared__ float sZ[64][33];
  __shared__ float sLog[64][13];
  __shared__ float sW[64][13];
  __shared__ int   sE[64], sD[64];
  __shared__ float cfs[12], mh[12], sh[12], rh[12], mch[12], sqq[12];
  __shared__ float sAgg[289];

  const int n = blockIdx.x, t = threadIdx.x;
  const int beg = rowptr[n], end = rowptr[n+1];
  const int lane = t & 63, wid = t >> 6;
  const float inv_sqrt3 = 0.57735026919f;

  if (t < 12) { cfs[t] = log1pf(expf(spc[t])) * (1.f/12.f); mh[t] = -1e30f; sh[t] = 0.f; sqq[t] = 0.f; }
  for (int i = t; i < 384; i += 256) {
    int c = i / 12, h = i - 12*c;
    wpT[h*33 + c] = Wpair[i] * inv_sqrt3;
  }
  __syncthreads();
  for (int s = t; s < 288; s += 256) {          // FIX: was `if (t < 288)` with 256 threads
    float v = ldp(&Ppts[(size_t)n*PTS_COLS + s]);   // qp global
    atomicAdd(&sqq[s/24], v*v);
  }
  __syncthreads();
  // build Qe in LDS: [ sqrt(1/3)/sqrt(32)*q | 2*cf*sqrt(1/3)*qp | 0 | Aconst | 0 x6 ]
  #pragma unroll
  for (int u = 0; u < 3; u++) {
    int s = t + 256*u;
    int h = s >> 6, i = s & 63;
    float val = 0.f;
    if (i < 32)       val = 0.1020620726f * ldp(&Pqkv[(size_t)n*QKV_COLS + h*32 + i]);
    else if (i < 56)  val = 1.15470053838f * cfs[h] * ldp(&Ppts[(size_t)n*PTS_COLS + h*24 + (i-32)]);
    else if (i == 57) val = -inv_sqrt3 * cfs[h] * sqq[h];
    qe[s] = val;
  }
  __syncthreads();
  // per-lane fixed Qe registers
  float q0[8], q1[8];
  #pragma unroll
  for (int i = 0; i < 8; i++) q0[i] = qe[8*lane + i];
  #pragma unroll
  for (int i = 0; i < 8; i++) q1[i] = (lane < 32) ? qe[512 + 8*lane + i] : 0.f;

  // slot -> head classes
  const int h0 = t >> 5;
  const int h1 = (t < 128) ? (8 + (t >> 5)) : ((t - 128) >> 5);
  const int h2 = 4 + (t >> 5);
  const int h3 = t / 24;
  const int h4 = (t < 32) ? ((t + 256) / 24) : 0;
  const int zc = t & 31;
  float a0 = 0.f, a1 = 0.f, a2 = 0.f, a3 = 0.f, a4 = 0.f;

  for (int c0 = beg; c0 < end; c0 += 64) {
    const int cn = min(64, end - c0);
    if (t < cn) { int e = eidx[c0 + t]; sE[t] = e; sD[t] = ei[EE + e]; }
    __syncthreads();
    // stage z rows (float4)
    #pragma unroll
    for (int u = 0; u < 2; u++) {
      int idx = t + 256*u;
      int j = idx >> 3, c4 = idx & 7;
      if (j < cn) {
        float4 zz = ((const float4*)(z + (size_t)sE[j]*32))[c4];
        sZ[j][c4*4+0] = zz.x; sZ[j][c4*4+1] = zz.y;
        sZ[j][c4*4+2] = zz.z; sZ[j][c4*4+3] = zz.w;
      }
    }
    __syncthreads();
    // pair logits into sLog (scaled by sqrt(1/3) via wpT)
    #pragma unroll
    for (int u = 0; u < 3; u++) {
      int idx = t + 256*u;
      int q = idx / 12, h = idx - 12*q;
      if (q < cn) {
        float acc = 0.f;
        #pragma unroll
        for (int c = 0; c < 32; c++) acc += sZ[q][c] * wpT[h*33 + c];
        sLog[q][h] = acc;
      }
    }
    __syncthreads();
    // phase 1: node+spatial dot via Ke gather, wave per edge
    for (int q = wid; q < cn; q += 4) {
      int dst = sD[q];
      const uint4* ke = (const uint4*)(KE + (size_t)dst*KE_COLS);
      float bc0 = 0.f, bc1 = 0.f;
      if ((lane & 7) == 0) {
        bc0 = SKKP[(size_t)dst*12 + (lane >> 3)];
        if (lane < 32) bc1 = SKKP[(size_t)dst*12 + 8 + (lane >> 3)];
      }
      uint4 L0 = ke[lane];
      uint4 L1 = make_uint4(0,0,0,0);
      if (lane < 32) L1 = ke[64 + lane];
      float p0 = dot8(q0, L0);
      p0 += __shfl_xor(p0, 1); p0 += __shfl_xor(p0, 2); p0 += __shfl_xor(p0, 4);
      float p1 = dot8(q1, L1);
      p1 += __shfl_xor(p1, 1); p1 += __shfl_xor(p1, 2); p1 += __shfl_xor(p1, 4);
      if ((lane & 7) == 0) {
        sLog[q][lane >> 3] += p0 + bc0;
        if (lane < 32) sLog[q][8 + (lane >> 3)] += p1 + bc1;
      }
    }
    __syncthreads();
    // chunk max per head (192 threads: h = t/16, i = t%16)
    if (t < 192) {
      int h = t >> 4, i = t & 15;
      float mx = -1e30f;
      for (int q = i; q < cn; q += 16) mx = fmaxf(mx, sLog[q][h]);
      #pragma unroll
      for (int m2 = 8; m2 >= 1; m2 >>= 1) mx = fmaxf(mx, __shfl_xor(mx, m2));
      if (i == 0) mch[h] = mx;
    }
    __syncthreads();
    if (t < 12) {
      float mn = fmaxf(mh[t], mch[t]);
      rh[t] = expf(mh[t] - mn);
      mh[t] = mn;
    }
    __syncthreads();
    // weights + running sum
    if (t < 192) {
      int h = t >> 4, i = t & 15;
      float ps = 0.f;
      for (int q = i; q < cn; q += 16) {
        float w = expf(sLog[q][h] - mh[h]);
        sW[q][h] = w;
        ps += w;
      }
      #pragma unroll
      for (int m2 = 8; m2 >= 1; m2 >>= 1) ps += __shfl_xor(ps, m2);
      if (i == 0) sh[h] = sh[h]*rh[h] + ps;
    }
    __syncthreads();
    // rescale accumulators, then phase 2 aggregation
    a0 *= rh[h0]; a1 *= rh[h1]; a2 *= rh[h2]; a3 *= rh[h3];
    if (t < 32) a4 *= rh[h4];
    #pragma unroll 2
    for (int q = 0; q < cn; q++) {
      int dst = sD[q];
      const TA* Pq = Pqkv + (size_t)dst*QKV_COLS;
      const TP* Pp = Ppts + (size_t)dst*PTS_COLS;
      float zval = sZ[q][zc];
      a0 += sW[q][h0] * zval;
      if (t < 128) a1 += sW[q][h1] * zval;
      else         a1 += sW[q][h1] * ldp(&Pq[640 + t]);
      a2 += sW[q][h2] * ldp(&Pq[896 + t]);
      a3 += sW[q][h3] * ldp(&Pp[576 + t]);
      if (t < 32) a4 += sW[q][h4] * ldp(&Pp[832 + t]);
    }
    __syncthreads();
  }
  // finalize: divide by sums
  if (t < 12) rh[t] = (sh[t] > 0.f) ? 1.f/sh[t] : 0.f;
  __syncthreads();
  a0 *= rh[h0]; a1 *= rh[h1]; a2 *= rh[h2]; a3 *= rh[h3];
  if (t < 32) a4 *= rh[h4];
  __hip_bfloat16* fr = featB + (size_t)n*FCOLS;
  fr[t]       = __float2bfloat16(a0);
  fr[256 + t] = __float2bfloat16(a1);
  fr[512 + t] = __float2bfloat16(a2);
  sAgg[t] = a3;
  if (t < 32) sAgg[256 + t] = a4;
  __syncthreads();
  if (t < 96) {
    int pt = t;
    const float* Rn = R + (size_t)n*9;
    float d0 = sAgg[pt*3+0] - tr[n*3+0];
    float d1 = sAgg[pt*3+1] - tr[n*3+1];
    float d2 = sAgg[pt*3+2] - tr[n*3+2];
    float l0 = Rn[0]*d0 + Rn[3]*d1 + Rn[6]*d2;
    float l1 = Rn[1]*d0 + Rn[4]*d1 + Rn[7]*d2;
    float l2 = Rn[2]*d0 + Rn[5]*d1 + Rn[8]*d2;
    float nr = sqrtf(l0*l0 + l1*l1 + l2*l2);
    float inv = 1.f / fmaxf(nr, 1e-8f);
    fr[768 + pt*3+0] = __float2bfloat16(l0);
    fr[768 + pt*3+1] = __float2bfloat16(l1);
    fr[768 + pt*3+2] = __float2bfloat16(l2);
    fr[1056 + pt]    = __float2bfloat16(nr);
    fr[1152 + pt*3+0] = __float2bfloat16(l0*inv);
    fr[1152 + pt*3+1] = __float2bfloat16(l1*inv);
    fr[1152 + pt*3+2] = __float2bfloat16(l2*inv);
  }
}

// ---------------- xo = x + featB @ Wo + bo   (32x128 tile, 4x4 register block)
__global__ __launch_bounds__(256) void wo_gemm(
    const __hip_bfloat16* __restrict__ featB, const float* __restrict__ Wo,
    const float* __restrict__ bo, const float* __restrict__ x, float* __restrict__ xo)
{
  __shared__ float Ast[32][36];
  __shared__ float Bs[32][132];
  const int t = threadIdx.x;
  const int n0 = blockIdx.x * 32;
  const int tx = t & 31, ty = t >> 5;
  const int cl = t & 127, kset = t >> 7;
  float acc[4][4] = {};
  const int ar = t >> 3, akc = (t & 7) * 4;
  for (int k0 = 0; k0 < FCOLS; k0 += 32) {
    {
      const __hip_bfloat16* ap = featB + (size_t)(n0 + ar)*FCOLS + k0 + akc;
      short4 raw = *(const short4*)(const void*)ap;
      Ast[akc+0][ar] = b2f((unsigned short)raw.x);
      Ast[akc+1][ar] = b2f((unsigned short)raw.y);
      Ast[akc+2][ar] = b2f((unsigned short)raw.z);
      Ast[akc+3][ar] = b2f((unsigned short)raw.w);
    }
    #pragma unroll
    for (int u = 0; u < 16; u++) {
      int kk = kset + 2*u;
      Bs[kk][cl] = Wo[(size_t)(k0 + kk)*128 + cl];
    }
    __syncthreads();
    #pragma unroll
    for (int kk = 0; kk < 32; kk++) {
      float4 a4 = *(const float4*)&Ast[kk][ty*4];
      float4 b4 = *(const float4*)&Bs[kk][tx*4];
      float av[4] = {a4.x, a4.y, a4.z, a4.w};
      float bv[4] = {b4.x, b4.y, b4.z, b4.w};
      #pragma unroll
      for (int i2 = 0; i2 < 4; i2++)
        #pragma unroll
        for (int j2 = 0; j2 < 4; j2++)
          acc[i2][j2] += av[i2] * bv[j2];
    }
    __syncthreads();
  }
  const int gc = tx*4;
  #pragma unroll
  for (int i2 = 0; i2 < 4; i2++) {
    int r = n0 + ty*4 + i2;
    float4 xr = *(const float4*)&x[(size_t)r*128 + gc];
    float xv[4] = {xr.x, xr.y, xr.z, xr.w};
    #pragma unroll
    for (int j2 = 0; j2 < 4; j2++)
      xo[(size_t)r*128 + gc + j2] = acc[i2][j2] + bo[gc + j2] + xv[j2];
  }
}

// ---------------- LN1 -> MLP -> residual -> LN2, 8 nodes per block
__global__ __launch_bounds__(256) void lnmlp(
    const float* __restrict__ xo,
    const float* __restrict__ g1, const float* __restrict__ b1v,
    const float* __restrict__ w1, const float* __restrict__ bb1,
    const float* __restrict__ w2, const float* __restrict__ bb2,
    const float* __restrict__ w3, const float* __restrict__ bb3,
    const float* __restrict__ g2, const float* __restrict__ b2v,
    float* __restrict__ out)
{
  __shared__ float hs[8][128];
  __shared__ float ms2[8][128];
  __shared__ float ys[8][128];
  __shared__ float mu_s[8], rs_s[8];
  int t = threadIdx.x;
  int n0 = blockIdx.x * 8;
  int c = t & 127, rset = t >> 7;
  int w = t >> 6, lane = t & 63;

  for (int r = rset; r < 8; r += 2) ys[r][c] = xo[(size_t)(n0+r)*128 + c];
  __syncthreads();
  for (int q = 0; q < 2; q++) {
    int r = w*2 + q;
    float v0 = ys[r][lane], v1 = ys[r][lane+64];
    float s = v0 + v1, ss = v0*v0 + v1*v1;
    #pragma unroll
    for (int m2 = 32; m2 >= 1; m2 >>= 1) { s += __shfl_xor(s, m2); ss += __shfl_xor(ss, m2); }
    if (lane == 0) { float mu = s*(1.f/128.f); mu_s[r] = mu; rs_s[r] = rsqrtf(ss*(1.f/128.f) - mu*mu + 1e-5f); }
  }
  __syncthreads();
  for (int r = rset; r < 8; r += 2) hs[r][c] = (ys[r][c] - mu_s[r]) * rs_s[r] * g1[c] + b1v[c];
  __syncthreads();
  {
    float acc[4] = {0,0,0,0};
    for (int i = 0; i < 128; i++) {
      float wv = w1[i*128 + c];
      #pragma unroll
      for (int j = 0; j < 4; j++) acc[j] += hs[rset*4+j][i] * wv;
    }
    #pragma unroll
    for (int j = 0; j < 4; j++) ms2[rset*4+j][c] = fmaxf(acc[j] + bb1[c], 0.f);
  }
  __syncthreads();
  {
    float acc[4] = {0,0,0,0};
    for (int i = 0; i < 128; i++) {
      float wv = w2[i*128 + c];
      #pragma unroll
      for (int j = 0; j < 4; j++) acc[j] += ms2[rset*4+j][i] * wv;
    }
    #pragma unroll
    for (int j = 0; j < 4; j++) ys[rset*4+j][c] = fmaxf(acc[j] + bb2[c], 0.f);
  }
  __syncthreads();
  {
    float acc[4] = {0,0,0,0};
    for (int i = 0; i < 128; i++) {
      float wv = w3[i*128 + c];
      #pragma unroll
      for (int j = 0; j < 4; j++) acc[j] += ys[rset*4+j][i] * wv;
    }
    #pragma unroll
    for (int j = 0; j < 4; j++) ms2[rset*4+j][c] = hs[rset*4+j][c] + acc[j] + bb3[c];
  }
  __syncthreads();
  for (int q = 0; q < 2; q++) {
    int r = w*2 + q;
    float v0 = ms2[r][lane], v1 = ms2[r][lane+64];
    float s = v0 + v1, ss = v0*v0 + v1*v1;
    #pragma unroll
    for (int m2 = 32; m2 >= 1; m2 >>= 1) { s += __shfl_xor(s, m2); ss += __shfl_xor(ss, m2); }
    if (lane == 0) { float mu = s*(1.f/128.f); mu_s[r] = mu; rs_s[r] = rsqrtf(ss*(1.f/128.f) - mu*mu + 1e-5f); }
  }
  __syncthreads();
  for (int r = rset; r < 8; r += 2)
    out[(size_t)(n0+r)*128 + c] = (ms2[r][c] - mu_s[r]) * rs_s[r] * g2[c] + b2v[c];
}

__global__ void diag_ws(float* out, float v)
{
  if (blockIdx.x == 0 && threadIdx.x == 0) out[0] = v;
}

// ---------------- host side ----------------
struct Args {
  const float *R, *tr, *x, *z, *Wq, *Wk, *Wv, *Wpair, *spc, *Wqp, *Wkp, *Wvp;
  const float *Wo, *bo, *g1, *b1v, *w1, *bb1, *w2, *bb2, *w3, *bb3, *g2, *b2v;
  const int* ei;
  float* out;
};

static inline size_t alup(size_t v) { return (v + 255) & ~(size_t)255; }

template<typename TA, typename TP>
static void run_all(const Args& a, char* ws, hipStream_t stream)
{
  size_t off = 0;
  TA* Pqkv = (TA*)(ws + off);        off += alup((size_t)NN*QKV_COLS*sizeof(TA));
  TP* Ppts = (TP*)(ws + off);        off += alup((size_t)NN*PTS_COLS*sizeof(TP));
  __hip_bfloat16* KE = (__hip_bfloat16*)(ws + off); off += alup((size_t)NN*KE_COLS*2);
  float* SKKP = (float*)(ws + off);  off += alup((size_t)NN*12*sizeof(float));
  int* cnt = (int*)(ws + off);       off += alup((size_t)NN*sizeof(int));
  int* rowptr = (int*)(ws + off);    off += alup((size_t)(NN+1)*sizeof(int));
  int* cursor = (int*)(ws + off);    off += alup((size_t)NN*sizeof(int));
  int* eidx = (int*)(ws + off);      off += alup((size_t)EE*sizeof(int));
  __hip_bfloat16* featB = (__hip_bfloat16*)(ws + off);
  float* xo = a.out;   // alias output buffer for the pre-LN activations

  hipMemsetAsync(cnt, 0, (size_t)NN*sizeof(int), stream);

  proj_gemm<TA,TP><<<dim3(NN/32, 16), 256, 0, stream>>>(a.x, a.Wq, a.Wk, a.Wv, a.Wqp, a.Wkp, a.Wvp, Pqkv, Ppts);
  transform_pts<TP><<<(NN*288)/256, 256, 0, stream>>>(a.R, a.tr, Ppts);
  count_edges<<<EE/256, 256, 0, stream>>>(a.ei, cnt);
  scan_csr<<<1, 1024, 0, stream>>>(cnt, rowptr, cursor);
  fill_csr<<<EE/256, 256, 0, stream>>>(a.ei, cursor, eidx);
  build_ke<TA,TP><<<NN, 256, 0, stream>>>(Pqkv, Ppts, a.spc, KE, SKKP);
  attn_fused<TA,TP><<<NN, 256, 0, stream>>>(Pqkv, Ppts, KE, SKKP, a.z, a.ei, a.Wpair, a.spc,
                                            rowptr, eidx, a.R, a.tr, featB);
  wo_gemm<<<NN/32, 256, 0, stream>>>(featB, a.Wo, a.bo, a.x, xo);
  lnmlp<<<NN/8, 256, 0, stream>>>(xo, a.g1, a.b1v, a.w1, a.bb1, a.w2, a.bb2,
                                  a.w3, a.bb3, a.g2, a.b2v, a.out);
}

extern "C" void kernel_launch(void* const* d_in, const int* in_sizes, int n_in,
                              void* d_out, int out_size, void* d_ws, size_t ws_size,
                              hipStream_t stream)
{
  Args a;
  a.R     = (const float*)d_in[0];
  a.tr    = (const float*)d_in[1];
  a.x     = (const float*)d_in[2];
  a.z     = (const float*)d_in[3];
  a.ei    = (const int*)  d_in[4];
  a.Wq    = (const float*)d_in[5];
  a.Wk    = (const float*)d_in[6];
  a.Wv    = (const float*)d_in[7];
  a.Wpair = (const float*)d_in[8];
  a.spc   = (const float*)d_in[9];
  a.Wqp   = (const float*)d_in[10];
  a.Wkp   = (const float*)d_in[11];
  a.Wvp   = (const float*)d_in[12];
  a.Wo    = (const float*)d_in[13];
  a.bo    = (const float*)d_in[14];
  a.g1    = (const float*)d_in[15];
  a.b1v   = (const float*)d_in[16];
  a.w1    = (const float*)d_in[17];
  a.bb1   = (const float*)d_in[18];
  a.w2    = (const float*)d_in[19];
  a.bb2   = (const float*)d_in[20];
  a.w3    = (const float*)d_in[21];
  a.bb3   = (const float*)d_in[22];
  a.g2    = (const float*)d_in[23];
  a.b2v   = (const float*)d_in[24];
  a.out   = (float*)d_out;

  size_t common = alup((size_t)NN*KE_COLS*2) + alup((size_t)NN*12*4) +
                  alup((size_t)NN*4)*2 + alup((size_t)(NN+1)*4) + alup((size_t)EE*4) +
                  alup((size_t)NN*FCOLS*2);
  size_t needA = alup((size_t)NN*QKV_COLS*4) + alup((size_t)NN*PTS_COLS*4) + common;
  size_t needB = alup((size_t)NN*QKV_COLS*2) + alup((size_t)NN*PTS_COLS*4) + common;
  size_t needC = alup((size_t)NN*QKV_COLS*2) + alup((size_t)NN*PTS_COLS*2) + common;

  if (ws_size >= needA)      run_all<float, float>(a, (char*)d_ws, stream);
  else if (ws_size >= needB) run_all<__hip_bfloat16, float>(a, (char*)d_ws, stream);
  else if (ws_size >= needC) run_all<__hip_bfloat16, __hip_bfloat16>(a, (char*)d_ws, stream);
  else diag_ws<<<1, 64, 0, stream>>>((float*)d_out, (float)((double)ws_size / (1024.0*1024.0)));
}

// Round 6
// 870.913 us; speedup vs baseline: 1.2398x; 1.2398x over previous
//
#include <hip/hip_runtime.h>
#include <hip/hip_bf16.h>
#include <math.h>

#define NN 20000
#define EE 320000
#define QKV_COLS 768    // [q 0..383 | k 384..767]
#define PTS_COLS 576    // [qp 0..287 | kp 288..575]
#define VE_COLS  672    // [v 384 | vp 288] bf16 always
#define FCOLS 1440      // [p2n 384 | node 384 | loc 288 | nrm 96 | dirn 288]
#define KE_COLS 768     // 12 heads x 64 [k 32 | kp 24 | 0 | 1 | 0 x6]

__device__ __forceinline__ float b2f(unsigned short u) {
  return __uint_as_float(((unsigned)u) << 16);
}

template<typename PT> __device__ __forceinline__ float ldp(const PT* p);
template<> __device__ __forceinline__ float ldp<float>(const float* p) { return *p; }
template<> __device__ __forceinline__ float ldp<__hip_bfloat16>(const __hip_bfloat16* p) { return __bfloat162float(*p); }
template<typename PT> __device__ __forceinline__ void stp(PT* p, float v);
template<> __device__ __forceinline__ void stp<float>(float* p, float v) { *p = v; }
template<> __device__ __forceinline__ void stp<__hip_bfloat16>(__hip_bfloat16* p, float v) { *p = __float2bfloat16(v); }

// ---------------- projections: x @ [Wq|Wk | Wv | Wqp|Wkp | Wvp] -> Pqkv | VE.v | Ppts | VE.vp
template<typename TA, typename TP>
__global__ __launch_bounds__(256) void proj_gemm(
    const float* __restrict__ x,
    const float* __restrict__ Wq, const float* __restrict__ Wk, const float* __restrict__ Wv,
    const float* __restrict__ Wqp, const float* __restrict__ Wkp, const float* __restrict__ Wvp,
    TA* __restrict__ Pqkv, TP* __restrict__ Ppts, __hip_bfloat16* __restrict__ VE)
{
  __shared__ float Ast[32][36];
  __shared__ float Bs[32][132];
  const int t = threadIdx.x;
  const int n0 = blockIdx.x * 32;
  const int c0 = blockIdx.y * 128;
  const int tx = t & 31, ty = t >> 5;
  const int cl = t & 127, kset = t >> 7;
  const int c = c0 + cl;
  const float* wcol = nullptr; int wstr = 0;
  if      (c < 384)  { wcol = Wq  + c;        wstr = 384; }
  else if (c < 768)  { wcol = Wk  + (c-384);  wstr = 384; }
  else if (c < 1152) { wcol = Wv  + (c-768);  wstr = 384; }
  else if (c < 1440) { wcol = Wqp + (c-1152); wstr = 288; }
  else if (c < 1728) { wcol = Wkp + (c-1440); wstr = 288; }
  else if (c < 2016) { wcol = Wvp + (c-1728); wstr = 288; }
  float acc[4][4] = {};
  const int ar = t >> 3, akc = (t & 7) * 4;
  for (int k0 = 0; k0 < 128; k0 += 32) {
    float4 av4 = *(const float4*)&x[(size_t)(n0 + ar)*128 + k0 + akc];
    Ast[akc+0][ar] = av4.x; Ast[akc+1][ar] = av4.y;
    Ast[akc+2][ar] = av4.z; Ast[akc+3][ar] = av4.w;
    #pragma unroll
    for (int u = 0; u < 16; u++) {
      int kk = kset + 2*u;
      Bs[kk][cl] = wcol ? wcol[(size_t)(k0 + kk)*wstr] : 0.f;
    }
    __syncthreads();
    #pragma unroll
    for (int kk = 0; kk < 32; kk++) {
      float4 a4 = *(const float4*)&Ast[kk][ty*4];
      float4 b4 = *(const float4*)&Bs[kk][tx*4];
      float av[4] = {a4.x, a4.y, a4.z, a4.w};
      float bv[4] = {b4.x, b4.y, b4.z, b4.w};
      #pragma unroll
      for (int i2 = 0; i2 < 4; i2++)
        #pragma unroll
        for (int j2 = 0; j2 < 4; j2++)
          acc[i2][j2] += av[i2] * bv[j2];
    }
    __syncthreads();
  }
  const int gc = c0 + tx*4;
  #pragma unroll
  for (int i2 = 0; i2 < 4; i2++) {
    int r = n0 + ty*4 + i2;
    if (gc < 768) {                 // q | k
      TA* dp = Pqkv + (size_t)r*QKV_COLS + gc;
      #pragma unroll
      for (int j2 = 0; j2 < 4; j2++) stp(&dp[j2], acc[i2][j2]);
    } else if (gc < 1152) {         // v -> VE[0..383] bf16
      __hip_bfloat16* dp = VE + (size_t)r*VE_COLS + (gc - 768);
      #pragma unroll
      for (int j2 = 0; j2 < 4; j2++) dp[j2] = __float2bfloat16(acc[i2][j2]);
    } else if (gc < 1728) {         // qp | kp (local)
      TP* dp = Ppts + (size_t)r*PTS_COLS + (gc - 1152);
      #pragma unroll
      for (int j2 = 0; j2 < 4; j2++) stp(&dp[j2], acc[i2][j2]);
    } else {                        // vp (local) -> VE[384..671] bf16
      __hip_bfloat16* dp = VE + (size_t)r*VE_COLS + 384 + (gc - 1728);
      #pragma unroll
      for (int j2 = 0; j2 < 4; j2++) if (gc + j2 < 2016) dp[j2] = __float2bfloat16(acc[i2][j2]);
    }
  }
}

// ---------------- point transform: qp/kp in Ppts (f32/TP), vp in VE (bf16), all in place
template<typename TP>
__global__ void transform_pts(const float* __restrict__ R, const float* __restrict__ tr,
                              TP* __restrict__ Ppts, __hip_bfloat16* __restrict__ VE)
{
  int idx = blockIdx.x*256 + threadIdx.x;   // N * 288 points
  if (idx >= NN*288) return;
  int n = idx / 288, rem = idx - n*288;
  const float* Rn = R + (size_t)n*9;
  float t0 = tr[n*3], t1 = tr[n*3+1], t2 = tr[n*3+2];
  if (rem < 192) {
    TP* p = Ppts + (size_t)n*PTS_COLS + rem*3;
    float l0 = ldp(p), l1 = ldp(p+1), l2 = ldp(p+2);
    stp(p,   Rn[0]*l0 + Rn[1]*l1 + Rn[2]*l2 + t0);
    stp(p+1, Rn[3]*l0 + Rn[4]*l1 + Rn[5]*l2 + t1);
    stp(p+2, Rn[6]*l0 + Rn[7]*l1 + Rn[8]*l2 + t2);
  } else {
    __hip_bfloat16* p = VE + (size_t)n*VE_COLS + 384 + (rem-192)*3;
    float l0 = __bfloat162float(p[0]), l1 = __bfloat162float(p[1]), l2 = __bfloat162float(p[2]);
    p[0] = __float2bfloat16(Rn[0]*l0 + Rn[1]*l1 + Rn[2]*l2 + t0);
    p[1] = __float2bfloat16(Rn[3]*l0 + Rn[4]*l1 + Rn[5]*l2 + t1);
    p[2] = __float2bfloat16(Rn[6]*l0 + Rn[7]*l1 + Rn[8]*l2 + t2);
  }
}

// ---------------- CSR build
__global__ void count_edges(const int* __restrict__ ei, int* __restrict__ cnt)
{
  int e = blockIdx.x*256 + threadIdx.x;
  if (e < EE) atomicAdd(&cnt[ei[e]], 1);
}

__global__ __launch_bounds__(1024) void scan_csr(const int* __restrict__ cnt,
                                                 int* __restrict__ rowptr,
                                                 int* __restrict__ cursor)
{
  __shared__ int part[1024];
  int t = threadIdx.x;
  int base = t*20;
  int loc[20];
  int s = 0;
  #pragma unroll
  for (int i = 0; i < 20; i++) {
    int idx = base + i;
    int cc = (idx < NN) ? cnt[idx] : 0;
    loc[i] = s; s += cc;
  }
  part[t] = s;
  __syncthreads();
  for (int off = 1; off < 1024; off <<= 1) {
    int v = (t >= off) ? part[t-off] : 0;
    __syncthreads();
    part[t] += v;
    __syncthreads();
  }
  int pre = (t == 0) ? 0 : part[t-1];
  #pragma unroll
  for (int i = 0; i < 20; i++) {
    int idx = base + i;
    if (idx < NN) { rowptr[idx] = pre + loc[i]; cursor[idx] = pre + loc[i]; }
  }
  if (t == 1023) rowptr[NN] = part[1023];
}

__global__ void fill_csr(const int* __restrict__ ei, int* __restrict__ cursor,
                         int* __restrict__ eidx)
{
  int e = blockIdx.x*256 + threadIdx.x;
  if (e >= EE) return;
  int pos = atomicAdd(&cursor[ei[e]], 1);
  eidx[pos] = e;
}

// ---------------- build Ke panel + SKKP (dst-side constants)
template<typename TA, typename TP>
__global__ __launch_bounds__(256) void build_ke(
    const TA* __restrict__ Pqkv, const TP* __restrict__ Ppts,
    const float* __restrict__ spc,
    __hip_bfloat16* __restrict__ KE, float* __restrict__ SKKP)
{
  __shared__ float skk[12], cfb[12];
  const int n = blockIdx.x, t = threadIdx.x;
  if (t < 12) { cfb[t] = log1pf(expf(spc[t])) * (1.f/12.f); skk[t] = 0.f; }
  __syncthreads();
  for (int s = t; s < 288; s += 256) {
    float v = ldp(&Ppts[(size_t)n*PTS_COLS + 288 + s]);
    atomicAdd(&skk[s/24], v*v);
  }
  __syncthreads();
  __hip_bfloat16* kr = KE + (size_t)n*KE_COLS;
  #pragma unroll
  for (int u = 0; u < 3; u++) {
    int s = t + 256*u;
    int h = s >> 6, i = s & 63;
    float val = 0.f;
    if (i < 32)       val = ldp(&Pqkv[(size_t)n*QKV_COLS + 384 + h*32 + i]);
    else if (i < 56)  val = ldp(&Ppts[(size_t)n*PTS_COLS + 288 + h*24 + (i-32)]);
    else if (i == 57) val = 1.0f;
    kr[s] = __float2bfloat16(val);
  }
  if (t < 12) SKKP[(size_t)n*12 + t] = -0.57735026919f * cfb[t] * skk[t];
}

__device__ __forceinline__ float dot8(const float* qr, uint4 v) {
  float s;
  s  = qr[0]*b2f((unsigned short)(v.x & 0xffffu));
  s += qr[1]*b2f((unsigned short)(v.x >> 16));
  s += qr[2]*b2f((unsigned short)(v.y & 0xffffu));
  s += qr[3]*b2f((unsigned short)(v.y >> 16));
  s += qr[4]*b2f((unsigned short)(v.z & 0xffffu));
  s += qr[5]*b2f((unsigned short)(v.z >> 16));
  s += qr[6]*b2f((unsigned short)(v.w & 0xffffu));
  s += qr[7]*b2f((unsigned short)(v.w >> 16));
  return s;
}

// ---------------- fused attention: logits + online softmax + vectorized aggregation
template<typename TA, typename TP>
__global__ __launch_bounds__(256) void attn_fused(
    const TA* __restrict__ Pqkv, const TP* __restrict__ Ppts,
    const __hip_bfloat16* __restrict__ KE, const float* __restrict__ SKKP,
    const __hip_bfloat16* __restrict__ VE,
    const float* __restrict__ z, const int* __restrict__ ei,
    const float* __restrict__ Wpair, const float* __restrict__ spc,
    const int* __restrict__ rowptr, const int* __restrict__ eidx,
    const float* __restrict__ R, const float* __restrict__ tr,
    __hip_bfloat16* __restrict__ featB)
{
  __shared__ float qe[768];
  __shared__ float wpT[12*33];
  __shared__ float sZ[64][33];
  __shared__ float sLA[64][13];   // pair-bias logits
  __shared__ float sLB[64][13];   // KE-dot logits
  __shared__ float sW[64][13];
  __shared__ int   sD[64];
  __shared__ float cfs[12], mh[12], sh[12], rh[12], mch[12], sqq[12];
  __shared__ float sVE[3][672];
  __shared__ float sAgg[288];

  const int n = blockIdx.x, t = threadIdx.x;
  const int beg = rowptr[n], end = rowptr[n+1];
  const int lane = t & 63, wid = t >> 6;
  const float inv_sqrt3 = 0.57735026919f;

  if (t < 12) { cfs[t] = log1pf(expf(spc[t])) * (1.f/12.f); mh[t] = -1e30f; sh[t] = 0.f; sqq[t] = 0.f; }
  for (int i = t; i < 384; i += 256) {
    int c = i / 12, h = i - 12*c;
    wpT[h*33 + c] = Wpair[i] * inv_sqrt3;
  }
  __syncthreads();
  for (int s = t; s < 288; s += 256) {
    float v = ldp(&Ppts[(size_t)n*PTS_COLS + s]);   // qp global
    atomicAdd(&sqq[s/24], v*v);
  }
  __syncthreads();
  // Qe: [ sqrt(1/3)/sqrt(32)*q | 2*cf*sqrt(1/3)*qp | 0 | Aconst | 0 x6 ]
  #pragma unroll
  for (int u = 0; u < 3; u++) {
    int s = t + 256*u;
    int h = s >> 6, i = s & 63;
    float val = 0.f;
    if (i < 32)       val = 0.1020620726f * ldp(&Pqkv[(size_t)n*QKV_COLS + h*32 + i]);
    else if (i < 56)  val = 1.15470053838f * cfs[h] * ldp(&Ppts[(size_t)n*PTS_COLS + h*24 + (i-32)]);
    else if (i == 57) val = -inv_sqrt3 * cfs[h] * sqq[h];
    qe[s] = val;
  }
  __syncthreads();
  float q0[8], q1[8];
  #pragma unroll
  for (int i = 0; i < 8; i++) q0[i] = qe[8*lane + i];
  #pragma unroll
  for (int i = 0; i < 8; i++) q1[i] = (lane < 32) ? qe[512 + 8*lane + i] : 0.f;

  // p2n mapping (LDS z) and VE mapping (3 groups x 84 threads, 8 slots each)
  const int h0 = t >> 5;
  const int h1 = 8 + (t >> 5);          // valid for t < 128
  const int zc = t & 31;
  const int g   = t / 84;               // 0..3 (g==3: 4 idle threads in VE loop)
  const int vth = t - g*84;
  const int s0  = vth*8;
  const int myh = (s0 < 384) ? (s0 >> 5) : ((s0 - 384) / 24);
  float a0 = 0.f, a1 = 0.f;
  float acc8[8] = {};

  for (int c0 = beg; c0 < end; c0 += 64) {
    const int cn = min(64, end - c0);
    __syncthreads();                          // protect sD/sZ/sW reuse
    if (t < cn) sD[t] = ei[EE + eidx[c0 + t]];
    #pragma unroll
    for (int u = 0; u < 2; u++) {             // stage z: 8 threads per row
      int idx = t + 256*u;
      int j = idx >> 3, c4 = idx & 7;
      if (j < cn) {
        int e = eidx[c0 + j];
        float4 zz = ((const float4*)(z + (size_t)e*32))[c4];
        sZ[j][c4*4+0] = zz.x; sZ[j][c4*4+1] = zz.y;
        sZ[j][c4*4+2] = zz.z; sZ[j][c4*4+3] = zz.w;
      }
    }
    __syncthreads();
    // pair logits -> sLA
    #pragma unroll
    for (int u = 0; u < 3; u++) {
      int idx = t + 256*u;
      int q = idx / 12, h = idx - 12*q;
      if (q < cn) {
        float acc = 0.f;
        #pragma unroll
        for (int c = 0; c < 32; c++) acc += sZ[q][c] * wpT[h*33 + c];
        sLA[q][h] = acc;
      }
    }
    // KE logits -> sLB (disjoint from sLA: no barrier needed between)
    #pragma unroll 2
    for (int q = wid; q < cn; q += 4) {
      int dst = sD[q];
      const uint4* ke = (const uint4*)(KE + (size_t)dst*KE_COLS);
      uint4 L0 = ke[lane];
      uint4 L1 = make_uint4(0,0,0,0);
      if (lane < 32) L1 = ke[64 + lane];
      float bc0 = 0.f, bc1 = 0.f;
      if ((lane & 7) == 0) {
        bc0 = SKKP[(size_t)dst*12 + (lane >> 3)];
        if (lane < 32) bc1 = SKKP[(size_t)dst*12 + 8 + (lane >> 3)];
      }
      float p0 = dot8(q0, L0);
      p0 += __shfl_xor(p0, 1); p0 += __shfl_xor(p0, 2); p0 += __shfl_xor(p0, 4);
      float p1 = dot8(q1, L1);
      p1 += __shfl_xor(p1, 1); p1 += __shfl_xor(p1, 2); p1 += __shfl_xor(p1, 4);
      if ((lane & 7) == 0) {
        sLB[q][lane >> 3] = p0 + bc0;
        if (lane < 32) sLB[q][8 + (lane >> 3)] = p1 + bc1;
      }
    }
    __syncthreads();
    // chunk max per head
    if (t < 192) {
      int h = t >> 4, i = t & 15;
      float mx = -1e30f;
      for (int q = i; q < cn; q += 16) mx = fmaxf(mx, sLA[q][h] + sLB[q][h]);
      #pragma unroll
      for (int m2 = 8; m2 >= 1; m2 >>= 1) mx = fmaxf(mx, __shfl_xor(mx, m2));
      if (i == 0) mch[h] = mx;
    }
    __syncthreads();
    if (t < 12) {
      float mn = fmaxf(mh[t], mch[t]);
      rh[t] = expf(mh[t] - mn);
      mh[t] = mn;
    }
    __syncthreads();
    // weights + running sum
    if (t < 192) {
      int h = t >> 4, i = t & 15;
      float ps = 0.f;
      for (int q = i; q < cn; q += 16) {
        float w = expf(sLA[q][h] + sLB[q][h] - mh[h]);
        sW[q][h] = w;
        ps += w;
      }
      #pragma unroll
      for (int m2 = 8; m2 >= 1; m2 >>= 1) ps += __shfl_xor(ps, m2);
      if (i == 0) sh[h] = sh[h]*rh[h] + ps;
    }
    __syncthreads();
    // rescale + aggregate
    a0 *= rh[h0];
    if (t < 128) a1 *= rh[h1];
    for (int q = 0; q < cn; q++) {
      float zv = sZ[q][zc];
      a0 += sW[q][h0] * zv;
      if (t < 128) a1 += sW[q][h1] * zv;
    }
    if (g < 3) {
      #pragma unroll
      for (int j = 0; j < 8; j++) acc8[j] *= rh[myh];
      #pragma unroll 2
      for (int qq = g; qq < cn; qq += 3) {
        float w = sW[qq][myh];
        const uint4* ve = (const uint4*)(VE + (size_t)sD[qq]*VE_COLS);
        uint4 L = ve[vth];
        acc8[0] += w * b2f((unsigned short)(L.x & 0xffffu));
        acc8[1] += w * b2f((unsigned short)(L.x >> 16));
        acc8[2] += w * b2f((unsigned short)(L.y & 0xffffu));
        acc8[3] += w * b2f((unsigned short)(L.y >> 16));
        acc8[4] += w * b2f((unsigned short)(L.z & 0xffffu));
        acc8[5] += w * b2f((unsigned short)(L.z >> 16));
        acc8[6] += w * b2f((unsigned short)(L.w & 0xffffu));
        acc8[7] += w * b2f((unsigned short)(L.w >> 16));
      }
    }
  }
  __syncthreads();   // all reads of rh/sh done before overwrite
  if (t < 12) rh[t] = (sh[t] > 0.f) ? 1.f/sh[t] : 0.f;
  __syncthreads();
  __hip_bfloat16* fr = featB + (size_t)n*FCOLS;
  a0 *= rh[h0];
  fr[t] = __float2bfloat16(a0);
  if (t < 128) { a1 *= rh[h1]; fr[256 + t] = __float2bfloat16(a1); }
  if (g < 3) {
    #pragma unroll
    for (int j = 0; j < 8; j++) sVE[g][s0 + j] = acc8[j] * rh[myh];
  }
  __syncthreads();
  for (int s = t; s < 672; s += 256) {
    float tot = sVE[0][s] + sVE[1][s] + sVE[2][s];
    if (s < 384) fr[384 + s] = __float2bfloat16(tot);
    else sAgg[s - 384] = tot;
  }
  __syncthreads();
  if (t < 96) {
    int pt = t;
    const float* Rn = R + (size_t)n*9;
    float d0 = sAgg[pt*3+0] - tr[n*3+0];
    float d1 = sAgg[pt*3+1] - tr[n*3+1];
    float d2 = sAgg[pt*3+2] - tr[n*3+2];
    float l0 = Rn[0]*d0 + Rn[3]*d1 + Rn[6]*d2;
    float l1 = Rn[1]*d0 + Rn[4]*d1 + Rn[7]*d2;
    float l2 = Rn[2]*d0 + Rn[5]*d1 + Rn[8]*d2;
    float nr = sqrtf(l0*l0 + l1*l1 + l2*l2);
    float inv = 1.f / fmaxf(nr, 1e-8f);
    fr[768 + pt*3+0] = __float2bfloat16(l0);
    fr[768 + pt*3+1] = __float2bfloat16(l1);
    fr[768 + pt*3+2] = __float2bfloat16(l2);
    fr[1056 + pt]    = __float2bfloat16(nr);
    fr[1152 + pt*3+0] = __float2bfloat16(l0*inv);
    fr[1152 + pt*3+1] = __float2bfloat16(l1*inv);
    fr[1152 + pt*3+2] = __float2bfloat16(l2*inv);
  }
}

// ---------------- xo = x + featB @ Wo + bo   (32x128 tile, 4x4 register block)
__global__ __launch_bounds__(256) void wo_gemm(
    const __hip_bfloat16* __restrict__ featB, const float* __restrict__ Wo,
    const float* __restrict__ bo, const float* __restrict__ x, float* __restrict__ xo)
{
  __shared__ float Ast[32][36];
  __shared__ float Bs[32][132];
  const int t = threadIdx.x;
  const int n0 = blockIdx.x * 32;
  const int tx = t & 31, ty = t >> 5;
  const int cl = t & 127, kset = t >> 7;
  float acc[4][4] = {};
  const int ar = t >> 3, akc = (t & 7) * 4;
  for (int k0 = 0; k0 < FCOLS; k0 += 32) {
    {
      const __hip_bfloat16* ap = featB + (size_t)(n0 + ar)*FCOLS + k0 + akc;
      short4 raw = *(const short4*)(const void*)ap;
      Ast[akc+0][ar] = b2f((unsigned short)raw.x);
      Ast[akc+1][ar] = b2f((unsigned short)raw.y);
      Ast[akc+2][ar] = b2f((unsigned short)raw.z);
      Ast[akc+3][ar] = b2f((unsigned short)raw.w);
    }
    #pragma unroll
    for (int u = 0; u < 16; u++) {
      int kk = kset + 2*u;
      Bs[kk][cl] = Wo[(size_t)(k0 + kk)*128 + cl];
    }
    __syncthreads();
    #pragma unroll
    for (int kk = 0; kk < 32; kk++) {
      float4 a4 = *(const float4*)&Ast[kk][ty*4];
      float4 b4 = *(const float4*)&Bs[kk][tx*4];
      float av[4] = {a4.x, a4.y, a4.z, a4.w};
      float bv[4] = {b4.x, b4.y, b4.z, b4.w};
      #pragma unroll
      for (int i2 = 0; i2 < 4; i2++)
        #pragma unroll
        for (int j2 = 0; j2 < 4; j2++)
          acc[i2][j2] += av[i2] * bv[j2];
    }
    __syncthreads();
  }
  const int gc = tx*4;
  #pragma unroll
  for (int i2 = 0; i2 < 4; i2++) {
    int r = n0 + ty*4 + i2;
    float4 xr = *(const float4*)&x[(size_t)r*128 + gc];
    float xv[4] = {xr.x, xr.y, xr.z, xr.w};
    #pragma unroll
    for (int j2 = 0; j2 < 4; j2++)
      xo[(size_t)r*128 + gc + j2] = acc[i2][j2] + bo[gc + j2] + xv[j2];
  }
}

// ---------------- LN1 -> MLP -> residual -> LN2, 8 nodes per block
__global__ __launch_bounds__(256) void lnmlp(
    const float* __restrict__ xo,
    const float* __restrict__ g1, const float* __restrict__ b1v,
    const float* __restrict__ w1, const float* __restrict__ bb1,
    const float* __restrict__ w2, const float* __restrict__ bb2,
    const float* __restrict__ w3, const float* __restrict__ bb3,
    const float* __restrict__ g2, const float* __restrict__ b2v,
    float* __restrict__ out)
{
  __shared__ float hs[8][128];
  __shared__ float ms2[8][128];
  __shared__ float ys[8][128];
  __shared__ float mu_s[8], rs_s[8];
  int t = threadIdx.x;
  int n0 = blockIdx.x * 8;
  int c = t & 127, rset = t >> 7;
  int w = t >> 6, lane = t & 63;

  for (int r = rset; r < 8; r += 2) ys[r][c] = xo[(size_t)(n0+r)*128 + c];
  __syncthreads();
  for (int q = 0; q < 2; q++) {
    int r = w*2 + q;
    float v0 = ys[r][lane], v1 = ys[r][lane+64];
    float s = v0 + v1, ss = v0*v0 + v1*v1;
    #pragma unroll
    for (int m2 = 32; m2 >= 1; m2 >>= 1) { s += __shfl_xor(s, m2); ss += __shfl_xor(ss, m2); }
    if (lane == 0) { float mu = s*(1.f/128.f); mu_s[r] = mu; rs_s[r] = rsqrtf(ss*(1.f/128.f) - mu*mu + 1e-5f); }
  }
  __syncthreads();
  for (int r = rset; r < 8; r += 2) hs[r][c] = (ys[r][c] - mu_s[r]) * rs_s[r] * g1[c] + b1v[c];
  __syncthreads();
  {
    float acc[4] = {0,0,0,0};
    for (int i = 0; i < 128; i++) {
      float wv = w1[i*128 + c];
      #pragma unroll
      for (int j = 0; j < 4; j++) acc[j] += hs[rset*4+j][i] * wv;
    }
    #pragma unroll
    for (int j = 0; j < 4; j++) ms2[rset*4+j][c] = fmaxf(acc[j] + bb1[c], 0.f);
  }
  __syncthreads();
  {
    float acc[4] = {0,0,0,0};
    for (int i = 0; i < 128; i++) {
      float wv = w2[i*128 + c];
      #pragma unroll
      for (int j = 0; j < 4; j++) acc[j] += ms2[rset*4+j][i] * wv;
    }
    #pragma unroll
    for (int j = 0; j < 4; j++) ys[rset*4+j][c] = fmaxf(acc[j] + bb2[c], 0.f);
  }
  __syncthreads();
  {
    float acc[4] = {0,0,0,0};
    for (int i = 0; i < 128; i++) {
      float wv = w3[i*128 + c];
      #pragma unroll
      for (int j = 0; j < 4; j++) acc[j] += ys[rset*4+j][i] * wv;
    }
    #pragma unroll
    for (int j = 0; j < 4; j++) ms2[rset*4+j][c] = hs[rset*4+j][c] + acc[j] + bb3[c];
  }
  __syncthreads();
  for (int q = 0; q < 2; q++) {
    int r = w*2 + q;
    float v0 = ms2[r][lane], v1 = ms2[r][lane+64];
    float s = v0 + v1, ss = v0*v0 + v1*v1;
    #pragma unroll
    for (int m2 = 32; m2 >= 1; m2 >>= 1) { s += __shfl_xor(s, m2); ss += __shfl_xor(ss, m2); }
    if (lane == 0) { float mu = s*(1.f/128.f); mu_s[r] = mu; rs_s[r] = rsqrtf(ss*(1.f/128.f) - mu*mu + 1e-5f); }
  }
  __syncthreads();
  for (int r = rset; r < 8; r += 2)
    out[(size_t)(n0+r)*128 + c] = (ms2[r][c] - mu_s[r]) * rs_s[r] * g2[c] + b2v[c];
}

__global__ void diag_ws(float* out, float v)
{
  if (blockIdx.x == 0 && threadIdx.x == 0) out[0] = v;
}

// ---------------- host side ----------------
struct Args {
  const float *R, *tr, *x, *z, *Wq, *Wk, *Wv, *Wpair, *spc, *Wqp, *Wkp, *Wvp;
  const float *Wo, *bo, *g1, *b1v, *w1, *bb1, *w2, *bb2, *w3, *bb3, *g2, *b2v;
  const int* ei;
  float* out;
};

static inline size_t alup(size_t v) { return (v + 255) & ~(size_t)255; }

template<typename TA, typename TP>
static void run_all(const Args& a, char* ws, hipStream_t stream)
{
  size_t off = 0;
  TA* Pqkv = (TA*)(ws + off);        off += alup((size_t)NN*QKV_COLS*sizeof(TA));
  TP* Ppts = (TP*)(ws + off);        off += alup((size_t)NN*PTS_COLS*sizeof(TP));
  __hip_bfloat16* VE = (__hip_bfloat16*)(ws + off); off += alup((size_t)NN*VE_COLS*2);
  __hip_bfloat16* KE = (__hip_bfloat16*)(ws + off); off += alup((size_t)NN*KE_COLS*2);
  float* SKKP = (float*)(ws + off);  off += alup((size_t)NN*12*sizeof(float));
  int* cnt = (int*)(ws + off);       off += alup((size_t)NN*sizeof(int));
  int* rowptr = (int*)(ws + off);    off += alup((size_t)(NN+1)*sizeof(int));
  int* cursor = (int*)(ws + off);    off += alup((size_t)NN*sizeof(int));
  int* eidx = (int*)(ws + off);      off += alup((size_t)EE*sizeof(int));
  __hip_bfloat16* featB = (__hip_bfloat16*)(ws + off);
  float* xo = a.out;   // alias output buffer for the pre-LN activations

  hipMemsetAsync(cnt, 0, (size_t)NN*sizeof(int), stream);

  proj_gemm<TA,TP><<<dim3(NN/32, 16), 256, 0, stream>>>(a.x, a.Wq, a.Wk, a.Wv, a.Wqp, a.Wkp, a.Wvp, Pqkv, Ppts, VE);
  transform_pts<TP><<<(NN*288)/256, 256, 0, stream>>>(a.R, a.tr, Ppts, VE);
  count_edges<<<EE/256, 256, 0, stream>>>(a.ei, cnt);
  scan_csr<<<1, 1024, 0, stream>>>(cnt, rowptr, cursor);
  fill_csr<<<EE/256, 256, 0, stream>>>(a.ei, cursor, eidx);
  build_ke<TA,TP><<<NN, 256, 0, stream>>>(Pqkv, Ppts, a.spc, KE, SKKP);
  attn_fused<TA,TP><<<NN, 256, 0, stream>>>(Pqkv, Ppts, KE, SKKP, VE, a.z, a.ei, a.Wpair, a.spc,
                                            rowptr, eidx, a.R, a.tr, featB);
  wo_gemm<<<NN/32, 256, 0, stream>>>(featB, a.Wo, a.bo, a.x, xo);
  lnmlp<<<NN/8, 256, 0, stream>>>(xo, a.g1, a.b1v, a.w1, a.bb1, a.w2, a.bb2,
                                  a.w3, a.bb3, a.g2, a.b2v, a.out);
}

extern "C" void kernel_launch(void* const* d_in, const int* in_sizes, int n_in,
                              void* d_out, int out_size, void* d_ws, size_t ws_size,
                              hipStream_t stream)
{
  Args a;
  a.R     = (const float*)d_in[0];
  a.tr    = (const float*)d_in[1];
  a.x     = (const float*)d_in[2];
  a.z     = (const float*)d_in[3];
  a.ei    = (const int*)  d_in[4];
  a.Wq    = (const float*)d_in[5];
  a.Wk    = (const float*)d_in[6];
  a.Wv    = (const float*)d_in[7];
  a.Wpair = (const float*)d_in[8];
  a.spc   = (const float*)d_in[9];
  a.Wqp   = (const float*)d_in[10];
  a.Wkp   = (const float*)d_in[11];
  a.Wvp   = (const float*)d_in[12];
  a.Wo    = (const float*)d_in[13];
  a.bo    = (const float*)d_in[14];
  a.g1    = (const float*)d_in[15];
  a.b1v   = (const float*)d_in[16];
  a.w1    = (const float*)d_in[17];
  a.bb1   = (const float*)d_in[18];
  a.w2    = (const float*)d_in[19];
  a.bb2   = (const float*)d_in[20];
  a.w3    = (const float*)d_in[21];
  a.bb3   = (const float*)d_in[22];
  a.g2    = (const float*)d_in[23];
  a.b2v   = (const float*)d_in[24];
  a.out   = (float*)d_out;

  size_t common = alup((size_t)NN*VE_COLS*2) + alup((size_t)NN*KE_COLS*2) + alup((size_t)NN*12*4) +
                  alup((size_t)NN*4)*2 + alup((size_t)(NN+1)*4) + alup((size_t)EE*4) +
                  alup((size_t)NN*FCOLS*2);
  size_t needA = alup((size_t)NN*QKV_COLS*4) + alup((size_t)NN*PTS_COLS*4) + common;
  size_t needB = alup((size_t)NN*QKV_COLS*2) + alup((size_t)NN*PTS_COLS*4) + common;
  size_t needC = alup((size_t)NN*QKV_COLS*2) + alup((size_t)NN*PTS_COLS*2) + common;

  if (ws_size >= needA)      run_all<float, float>(a, (char*)d_ws, stream);
  else if (ws_size >= needB) run_all<__hip_bfloat16, float>(a, (char*)d_ws, stream);
  else if (ws_size >= needC) run_all<__hip_bfloat16, __hip_bfloat16>(a, (char*)d_ws, stream);
  else diag_ws<<<1, 64, 0, stream>>>((float*)d_out, (float)((double)ws_size / (1024.0*1024.0)));
}